// Round 1
// 340.919 us; speedup vs baseline: 1.0735x; 1.0735x over previous
//
#include <hip/hip_runtime.h>

#define N_NODES 40000
#define N_EDGES 640000
#define IN_F 128
#define HID_F 256
#define CLS_F 40
#define MB 16     // nodes per block in fused MLP
#define TS_LD 258 // padded leading dim for ts: bank(258*m + j) = (2m + j) % 32 -> 16 distinct banks

// ---------------- CSR build ----------------

__global__ void k_count(const int* __restrict__ dst, int* __restrict__ counts) {
    int e = blockIdx.x * blockDim.x + threadIdx.x;
    if (e < N_EDGES) atomicAdd(&counts[dst[e]], 1);
}

__global__ void k_scan1(const int* __restrict__ counts, int* __restrict__ bsum) {
    __shared__ int s[256];
    int i = blockIdx.x * 256 + threadIdx.x;
    s[threadIdx.x] = (i < N_NODES) ? counts[i] : 0;
    __syncthreads();
    for (int off = 128; off > 0; off >>= 1) {
        if (threadIdx.x < off) s[threadIdx.x] += s[threadIdx.x + off];
        __syncthreads();
    }
    if (threadIdx.x == 0) bsum[blockIdx.x] = s[0];
}

__global__ void k_scan2(int* __restrict__ bsum, int nb) {
    if (blockIdx.x == 0 && threadIdx.x == 0) {
        int run = 0;
        for (int b = 0; b < nb; b++) { int t = bsum[b]; bsum[b] = run; run += t; }
    }
}

__global__ void k_scan3(const int* __restrict__ counts, const int* __restrict__ bsum,
                        int* __restrict__ rowptr, int* __restrict__ cursor) {
    __shared__ int s[256];
    int t = threadIdx.x;
    int i = blockIdx.x * 256 + t;
    int v = (i < N_NODES) ? counts[i] : 0;
    s[t] = v;
    __syncthreads();
    for (int off = 1; off < 256; off <<= 1) {
        int x = (t >= off) ? s[t - off] : 0;
        __syncthreads();
        s[t] += x;
        __syncthreads();
    }
    if (i < N_NODES) {
        int excl = s[t] - v + bsum[blockIdx.x];
        rowptr[i] = excl;
        cursor[i] = excl;
    }
}

__global__ void k_norm(const int* __restrict__ counts,
                       float* __restrict__ norm, float* __restrict__ norm2) {
    int i = blockIdx.x * blockDim.x + threadIdx.x;
    if (i < N_NODES) {
        float d = (float)counts[i];
        float r = rsqrtf(fmaxf(d, 1.0f));
        norm[i] = r;
        norm2[i] = r * r;
    }
}

__global__ void k_fill(const int* __restrict__ src, const int* __restrict__ dst,
                       int* __restrict__ cursor, int* __restrict__ csr_src) {
    int e = blockIdx.x * blockDim.x + threadIdx.x;
    if (e < N_EDGES) {
        int d = dst[e];
        int p = atomicAdd(&cursor[d], 1);
        csr_src[p] = src[e];
    }
}

// ---------------- propagation hop (gather, no atomics) ----------------
// out[n][:] = sum_{e in in-edges(n)} in[src(e)][:] * scale[src(e)]
// 32 lanes per node, float4 per lane -> one coalesced 512B row read per edge.

__global__ __launch_bounds__(256) void k_hop(
        const float* __restrict__ gin, float* __restrict__ gout,
        const int* __restrict__ csr_src, const int* __restrict__ rowptr,
        const int* __restrict__ counts, const float* __restrict__ scale) {
    int gid  = blockIdx.x * 8 + (threadIdx.x >> 5);
    int lane = threadIdx.x & 31;
    if (gid >= N_NODES) return;
    int start = rowptr[gid];
    int cnt   = counts[gid];
    float4 acc = make_float4(0.f, 0.f, 0.f, 0.f);
    for (int i = 0; i < cnt; i++) {
        int s = csr_src[start + i];
        float sc = scale[s];
        float4 v = ((const float4*)(gin + (size_t)s * IN_F))[lane];
        acc.x = fmaf(v.x, sc, acc.x);
        acc.y = fmaf(v.y, sc, acc.y);
        acc.z = fmaf(v.z, sc, acc.z);
        acc.w = fmaf(v.w, sc, acc.w);
    }
    ((float4*)(gout + (size_t)gid * IN_F))[lane] = acc;
}

// ---------------- fused MLP: (h2*norm) @ W1 + b1 -> relu -> @ W2 + b2 ----------------
//
// GEMM1: thread t owns hidden column t for all MB rows (unchanged structure,
//        + manual W1 software pipeline, + vectorized load phase).
// GEMM2: W2 staged into LDS in [j][c] layout in two 128-row halves reusing the
//        hs buffer (dead after GEMM1). Task (m, c4): thread owns row m and 4
//        output classes; inner loop = 1 broadcast ts read + 1 conflict-free
//        ds_read_b128 of W2 + 4 FMAs. No global loads, no 64-bit addr math.

__global__ __launch_bounds__(256) void k_mlp(
        const float* __restrict__ h2, const float* __restrict__ norm,
        const float* __restrict__ W1, const float* __restrict__ b1,
        const float* __restrict__ W2, const float* __restrict__ b2,
        float* __restrict__ out) {
    __shared__ __align__(16) float buf[5120];        // 20KB: hs (2048 floats) then W2 halves (5120)
    __shared__ __align__(16) float ts[MB * TS_LD];   // 16.5KB padded
    int n0 = blockIdx.x * MB;
    int t  = threadIdx.x;

    // ---- load phase: hs[m][k] = h2[n0+m][k] * norm[n0+m], float4-vectorized ----
    const float4* h2_4 = (const float4*)(h2 + (size_t)n0 * IN_F);
    float4* hs4 = (float4*)buf;
    #pragma unroll
    for (int r = 0; r < 2; r++) {
        int idx4 = t + r * 256;          // 0..511 (= m*32 + kk)
        float4 v = h2_4[idx4];
        float s = norm[n0 + (idx4 >> 5)];
        v.x *= s; v.y *= s; v.z *= s; v.w *= s;
        hs4[idx4] = v;
    }
    __syncthreads();

    // ---- GEMM1: hidden[m][t] = sum_k hs[m][k] * W1[k][t] ----
    float acc[MB];
    #pragma unroll
    for (int m = 0; m < MB; m++) acc[m] = 0.f;

    const float* wp = W1 + t;            // column t, row stride HID_F
    float wa0 = wp[0], wa1 = wp[HID_F], wa2 = wp[2 * HID_F], wa3 = wp[3 * HID_F];
    #pragma unroll 1
    for (int k4 = 0; ; k4++) {
        float wb0, wb1, wb2, wb3;
        if (k4 < 31) {                   // software-pipeline next 4 weight rows
            const float* wq = wp + (k4 + 1) * (4 * HID_F);
            wb0 = wq[0]; wb1 = wq[HID_F]; wb2 = wq[2 * HID_F]; wb3 = wq[3 * HID_F];
        }
        #pragma unroll
        for (int m = 0; m < MB; m++) {
            float4 h4 = hs4[m * 32 + k4];    // wave-uniform address -> LDS broadcast
            acc[m] = fmaf(h4.x, wa0, acc[m]);
            acc[m] = fmaf(h4.y, wa1, acc[m]);
            acc[m] = fmaf(h4.z, wa2, acc[m]);
            acc[m] = fmaf(h4.w, wa3, acc[m]);
        }
        if (k4 == 31) break;
        wa0 = wb0; wa1 = wb1; wa2 = wb2; wa3 = wb3;
    }

    float bb = b1[t];
    #pragma unroll
    for (int m = 0; m < MB; m++) {
        float v = acc[m] + bb;
        ts[m * TS_LD + t] = v > 0.f ? v : 0.f;
    }
    __syncthreads();                     // ts ready; hs region of buf now dead

    // ---- GEMM2: out[m][4c4..4c4+3] = sum_j ts[m][j] * W2[j][c] + b2 ----
    int   m    = t & 15;
    int   c4   = t >> 4;                 // valid when t < 160
    bool  active = (t < 160);
    const float* tsr = ts + m * TS_LD;
    float4* w2s4 = (float4*)buf;
    float4 oacc = make_float4(0.f, 0.f, 0.f, 0.f);

    #pragma unroll
    for (int half = 0; half < 2; half++) {
        // stage 128 rows of W2 (5120 floats = 1280 float4) into buf, coalesced copy
        const float4* w2g = (const float4*)(W2 + half * 128 * CLS_F);
        #pragma unroll
        for (int r = 0; r < 5; r++) w2s4[t + r * 256] = w2g[t + r * 256];
        __syncthreads();
        if (active) {
            const float* tsh = tsr + half * 128;
            #pragma unroll 8
            for (int j = 0; j < 128; j++) {
                float  a = tsh[j];               // 16 distinct banks (TS_LD=258), broadcast x4
                float4 w = w2s4[j * 10 + c4];    // 4 distinct addrs/wave -> conflict-free
                oacc.x = fmaf(a, w.x, oacc.x);
                oacc.y = fmaf(a, w.y, oacc.y);
                oacc.z = fmaf(a, w.z, oacc.z);
                oacc.w = fmaf(a, w.w, oacc.w);
            }
        }
        __syncthreads();                 // half's reads done before restage
    }

    if (active) {
        float4 bv = ((const float4*)b2)[c4];
        oacc.x += bv.x; oacc.y += bv.y; oacc.z += bv.z; oacc.w += bv.w;
        ((float4*)(out + (size_t)(n0 + m) * CLS_F))[c4] = oacc;
    }
}

// ---------------- launch ----------------

extern "C" void kernel_launch(void* const* d_in, const int* in_sizes, int n_in,
                              void* d_out, int out_size, void* d_ws, size_t ws_size,
                              hipStream_t stream) {
    const float* features = (const float*)d_in[0];
    const int*   src      = (const int*)d_in[1];
    const int*   dst      = (const int*)d_in[2];
    const float* W1       = (const float*)d_in[3];
    const float* b1       = (const float*)d_in[4];
    const float* W2       = (const float*)d_in[5];
    const float* b2       = (const float*)d_in[6];
    float*       out      = (float*)d_out;

    char* ws = (char*)d_ws;
    size_t off = 0;
    auto alloc = [&](size_t bytes) -> void* {
        void* p = ws + off;
        off += (bytes + 255) & ~(size_t)255;
        return p;
    };
    int*   counts = (int*)alloc((size_t)N_NODES * 4);
    int*   rowptr = (int*)alloc((size_t)N_NODES * 4);
    int*   cursor = (int*)alloc((size_t)N_NODES * 4);
    int*   bsum   = (int*)alloc(256 * 4);
    float* norm   = (float*)alloc((size_t)N_NODES * 4);
    float* norm2  = (float*)alloc((size_t)N_NODES * 4);
    int*   csr    = (int*)alloc((size_t)N_EDGES * 4);
    float* h1     = (float*)alloc((size_t)N_NODES * IN_F * 4);
    float* h2     = (float*)alloc((size_t)N_NODES * IN_F * 4);

    hipMemsetAsync(counts, 0, (size_t)N_NODES * 4, stream);

    int nb = (N_NODES + 255) / 256;   // 157
    k_count<<<(N_EDGES + 255) / 256, 256, 0, stream>>>(dst, counts);
    k_scan1<<<nb, 256, 0, stream>>>(counts, bsum);
    k_scan2<<<1, 64, 0, stream>>>(bsum, nb);
    k_scan3<<<nb, 256, 0, stream>>>(counts, bsum, rowptr, cursor);
    k_norm<<<nb, 256, 0, stream>>>(counts, norm, norm2);
    k_fill<<<(N_EDGES + 255) / 256, 256, 0, stream>>>(src, dst, cursor, csr);

    // hop1: scale by norm[src]; hop2: scale by norm^2[src]; trailing norm folded into MLP
    k_hop<<<(N_NODES + 7) / 8, 256, 0, stream>>>(features, h1, csr, rowptr, counts, norm);
    k_hop<<<(N_NODES + 7) / 8, 256, 0, stream>>>(h1, h2, csr, rowptr, counts, norm2);

    k_mlp<<<N_NODES / MB, 256, 0, stream>>>(h2, norm, W1, b1, W2, b2, out);
}

// Round 2
// 339.356 us; speedup vs baseline: 1.0785x; 1.0046x over previous
//
#include <hip/hip_runtime.h>

#define N_NODES 40000
#define N_EDGES 640000
#define IN_F 128
#define HID_F 256
#define CLS_F 40
#define CLS_P 48      // padded to 3 MFMA tiles of 16
#define MB 32         // nodes per block in fused MLP
#define TS_LD 264     // ushort row stride for relu intermediate (bank spread)

typedef __attribute__((ext_vector_type(8))) short bf16x8;
typedef __attribute__((ext_vector_type(4))) float f32x4;

#define MFMA(a, b, c) __builtin_amdgcn_mfma_f32_16x16x32_bf16(a, b, c, 0, 0, 0)

__device__ __forceinline__ unsigned short f32_to_bf16_rne(float f) {
    unsigned int u = __float_as_uint(f);
    unsigned int r = u + 0x7fffu + ((u >> 16) & 1u);
    return (unsigned short)(r >> 16);
}

// ---------------- CSR build ----------------

__global__ void k_count(const int* __restrict__ dst, int* __restrict__ counts) {
    int e = blockIdx.x * blockDim.x + threadIdx.x;
    if (e < N_EDGES) atomicAdd(&counts[dst[e]], 1);
}

__global__ void k_scan1(const int* __restrict__ counts, int* __restrict__ bsum) {
    __shared__ int s[256];
    int i = blockIdx.x * 256 + threadIdx.x;
    s[threadIdx.x] = (i < N_NODES) ? counts[i] : 0;
    __syncthreads();
    for (int off = 128; off > 0; off >>= 1) {
        if (threadIdx.x < off) s[threadIdx.x] += s[threadIdx.x + off];
        __syncthreads();
    }
    if (threadIdx.x == 0) bsum[blockIdx.x] = s[0];
}

__global__ void k_scan2(int* __restrict__ bsum, int nb) {
    if (blockIdx.x == 0 && threadIdx.x == 0) {
        int run = 0;
        for (int b = 0; b < nb; b++) { int t = bsum[b]; bsum[b] = run; run += t; }
    }
}

__global__ void k_scan3(const int* __restrict__ counts, const int* __restrict__ bsum,
                        int* __restrict__ rowptr, int* __restrict__ cursor) {
    __shared__ int s[256];
    int t = threadIdx.x;
    int i = blockIdx.x * 256 + t;
    int v = (i < N_NODES) ? counts[i] : 0;
    s[t] = v;
    __syncthreads();
    for (int off = 1; off < 256; off <<= 1) {
        int x = (t >= off) ? s[t - off] : 0;
        __syncthreads();
        s[t] += x;
        __syncthreads();
    }
    if (i < N_NODES) {
        int excl = s[t] - v + bsum[blockIdx.x];
        rowptr[i] = excl;
        cursor[i] = excl;
    }
}

__global__ void k_norm(const int* __restrict__ counts,
                       float* __restrict__ norm, float* __restrict__ norm2) {
    int i = blockIdx.x * blockDim.x + threadIdx.x;
    if (i < N_NODES) {
        float d = (float)counts[i];
        float r = rsqrtf(fmaxf(d, 1.0f));
        norm[i] = r;
        norm2[i] = r * r;
    }
}

__global__ void k_fill(const int* __restrict__ src, const int* __restrict__ dst,
                       int* __restrict__ cursor, int* __restrict__ csr_src) {
    int e = blockIdx.x * blockDim.x + threadIdx.x;
    if (e < N_EDGES) {
        int d = dst[e];
        int p = atomicAdd(&cursor[d], 1);
        csr_src[p] = src[e];
    }
}

// ---------------- weight prep: split fp32 -> bf16 hi/lo, transposed [col][k] ----------------
// w1hi/w1lo: [HID_F][IN_F] bf16;  w2hi/w2lo: [CLS_P][HID_F] bf16 (cols >= 40 zeroed)

__global__ __launch_bounds__(256) void k_prep(
        const float* __restrict__ W1, const float* __restrict__ W2,
        unsigned short* __restrict__ w1hi, unsigned short* __restrict__ w1lo,
        unsigned short* __restrict__ w2hi, unsigned short* __restrict__ w2lo) {
    int idx = blockIdx.x * 256 + threadIdx.x;
    if (idx < IN_F * HID_F) {
        int k = idx >> 8;            // row of W1 (k index)
        int c = idx & 255;           // col of W1
        float v = W1[idx];
        unsigned short hi = f32_to_bf16_rne(v);
        float fh = __uint_as_float((unsigned)hi << 16);
        unsigned short lo = f32_to_bf16_rne(v - fh);
        w1hi[c * IN_F + k] = hi;
        w1lo[c * IN_F + k] = lo;
    }
    int idx2 = idx - IN_F * HID_F;
    if (idx2 >= 0 && idx2 < CLS_P * HID_F) {
        int c = idx2 >> 8;           // 0..47
        int k = idx2 & 255;
        float v = (c < CLS_F) ? W2[k * CLS_F + c] : 0.f;
        unsigned short hi = f32_to_bf16_rne(v);
        float fh = __uint_as_float((unsigned)hi << 16);
        unsigned short lo = f32_to_bf16_rne(v - fh);
        w2hi[c * HID_F + k] = hi;
        w2lo[c * HID_F + k] = lo;
    }
}

// ---------------- propagation hop (gather, no atomics) ----------------

__global__ __launch_bounds__(256) void k_hop(
        const float* __restrict__ gin, float* __restrict__ gout,
        const int* __restrict__ csr_src, const int* __restrict__ rowptr,
        const int* __restrict__ counts, const float* __restrict__ scale) {
    int gid  = blockIdx.x * 8 + (threadIdx.x >> 5);
    int lane = threadIdx.x & 31;
    if (gid >= N_NODES) return;
    int start = rowptr[gid];
    int cnt   = counts[gid];
    float4 acc = make_float4(0.f, 0.f, 0.f, 0.f);
    for (int i = 0; i < cnt; i++) {
        int s = csr_src[start + i];
        float sc = scale[s];
        float4 v = ((const float4*)(gin + (size_t)s * IN_F))[lane];
        acc.x = fmaf(v.x, sc, acc.x);
        acc.y = fmaf(v.y, sc, acc.y);
        acc.z = fmaf(v.z, sc, acc.z);
        acc.w = fmaf(v.w, sc, acc.w);
    }
    ((float4*)(gout + (size_t)gid * IN_F))[lane] = acc;
}

// ---------------- fused MLP via split-bf16 MFMA ----------------
// D = Ahi*Bhi + Ahi*Blo + Alo*Bhi  (fp32 accum), error ~2^-18 relative.
// Fragment convention: row/col = lane&15, k = (lane>>4)*8 + i  (A and B share
// the same k-map, so any consistent ordering gives the exact dot product).
// Block = 256 thr = 4 waves, MB=32 rows. Wave w: rows (w&1)*16.., cols (w>>1)*128..
// GEMM1 A from global h2 (k-contiguous 16B loads), B from prepped w1 (16B loads, L2-hot).
// relu intermediate -> LDS as separate hi/lo ushort planes -> GEMM2 A frags are
// single ds_read_b128, zero unpack VALU.

__global__ __launch_bounds__(256) void k_mlp(
        const float* __restrict__ h2, const float* __restrict__ norm,
        const unsigned short* __restrict__ w1hi, const unsigned short* __restrict__ w1lo,
        const float* __restrict__ b1,
        const unsigned short* __restrict__ w2hi, const unsigned short* __restrict__ w2lo,
        const float* __restrict__ b2,
        float* __restrict__ out) {
    __shared__ __align__(16) unsigned short tshi[MB * TS_LD];  // 16.5 KB
    __shared__ __align__(16) unsigned short tslo[MB * TS_LD];  // 16.5 KB
    int n0 = blockIdx.x * MB;
    int t  = threadIdx.x;
    int w  = t >> 6;
    int l  = t & 63;
    int lr = l & 15;     // A-row / B-col within tile
    int lg = l >> 4;     // k-group

    int rt      = w & 1;            // row-tile of this wave (GEMM1)
    int colbase = (w >> 1) * 128;   // col half of this wave (GEMM1)

    // ---- A fragments for GEMM1: h2[row][k] * norm[row], split hi/lo ----
    int arow = n0 + rt * 16 + lr;
    float nrm = norm[arow];
    const float* hrow = h2 + (size_t)arow * IN_F;
    bf16x8 ah[4], al[4];
    #pragma unroll
    for (int kq = 0; kq < 4; kq++) {
        int kb = kq * 32 + lg * 8;
        float4 v0 = *(const float4*)(hrow + kb);
        float4 v1 = *(const float4*)(hrow + kb + 4);
        float vv[8] = {v0.x, v0.y, v0.z, v0.w, v1.x, v1.y, v1.z, v1.w};
        #pragma unroll
        for (int i = 0; i < 8; i++) {
            float f = vv[i] * nrm;
            unsigned short hi = f32_to_bf16_rne(f);
            float fh = __uint_as_float((unsigned)hi << 16);
            unsigned short lo = f32_to_bf16_rne(f - fh);
            ah[kq][i] = (short)hi;
            al[kq][i] = (short)lo;
        }
    }

    // ---- GEMM1: 8 col-tiles x 4 k-steps x 3 MFMA; epilogue -> relu -> LDS hi/lo ----
    for (int ct = 0; ct < 8; ct++) {
        int col = colbase + ct * 16 + lr;
        const unsigned short* bhp = w1hi + (size_t)col * IN_F + lg * 8;
        const unsigned short* blp = w1lo + (size_t)col * IN_F + lg * 8;
        f32x4 acc = {0.f, 0.f, 0.f, 0.f};
        #pragma unroll
        for (int kq = 0; kq < 4; kq++) {
            bf16x8 bh = *(const bf16x8*)(bhp + kq * 32);
            bf16x8 bl = *(const bf16x8*)(blp + kq * 32);
            acc = MFMA(ah[kq], bh, acc);
            acc = MFMA(ah[kq], bl, acc);
            acc = MFMA(al[kq], bh, acc);
        }
        float bias = b1[col];
        #pragma unroll
        for (int r = 0; r < 4; r++) {
            int row = rt * 16 + lg * 4 + r;        // C layout: row=(lane>>4)*4+reg
            float v = acc[r] + bias;
            v = v > 0.f ? v : 0.f;
            unsigned short hi = f32_to_bf16_rne(v);
            float fh = __uint_as_float((unsigned)hi << 16);
            unsigned short lo = f32_to_bf16_rne(v - fh);
            tshi[row * TS_LD + col] = hi;
            tslo[row * TS_LD + col] = lo;
        }
    }
    __syncthreads();

    // ---- GEMM2: 6 tiles (2 row-tiles x 3 col-tiles) over 4 waves ----
    for (int id = w; id < 6; id += 4) {
        int rt2 = id / 3, ct2 = id % 3;
        int col = ct2 * 16 + lr;                   // 0..47 (padded)
        const unsigned short* ahp = tshi + (rt2 * 16 + lr) * TS_LD + lg * 8;
        const unsigned short* alp = tslo + (rt2 * 16 + lr) * TS_LD + lg * 8;
        const unsigned short* bhp = w2hi + (size_t)col * HID_F + lg * 8;
        const unsigned short* blp = w2lo + (size_t)col * HID_F + lg * 8;
        f32x4 acc = {0.f, 0.f, 0.f, 0.f};
        #pragma unroll
        for (int kk = 0; kk < 8; kk++) {
            bf16x8 a_h = *(const bf16x8*)(ahp + kk * 32);
            bf16x8 a_l = *(const bf16x8*)(alp + kk * 32);
            bf16x8 b_h = *(const bf16x8*)(bhp + kk * 32);
            bf16x8 b_l = *(const bf16x8*)(blp + kk * 32);
            acc = MFMA(a_h, b_h, acc);
            acc = MFMA(a_h, b_l, acc);
            acc = MFMA(a_l, b_h, acc);
        }
        if (col < CLS_F) {
            float bias = b2[col];
            #pragma unroll
            for (int r = 0; r < 4; r++) {
                int mrow = n0 + rt2 * 16 + lg * 4 + r;
                out[(size_t)mrow * CLS_F + col] = acc[r] + bias;
            }
        }
    }
}

// ---------------- launch ----------------

extern "C" void kernel_launch(void* const* d_in, const int* in_sizes, int n_in,
                              void* d_out, int out_size, void* d_ws, size_t ws_size,
                              hipStream_t stream) {
    const float* features = (const float*)d_in[0];
    const int*   src      = (const int*)d_in[1];
    const int*   dst      = (const int*)d_in[2];
    const float* W1       = (const float*)d_in[3];
    const float* b1       = (const float*)d_in[4];
    const float* W2       = (const float*)d_in[5];
    const float* b2       = (const float*)d_in[6];
    float*       out      = (float*)d_out;

    char* ws = (char*)d_ws;
    size_t off = 0;
    auto alloc = [&](size_t bytes) -> void* {
        void* p = ws + off;
        off += (bytes + 255) & ~(size_t)255;
        return p;
    };
    int*   counts = (int*)alloc((size_t)N_NODES * 4);
    int*   rowptr = (int*)alloc((size_t)N_NODES * 4);
    int*   cursor = (int*)alloc((size_t)N_NODES * 4);
    int*   bsum   = (int*)alloc(256 * 4);
    float* norm   = (float*)alloc((size_t)N_NODES * 4);
    float* norm2  = (float*)alloc((size_t)N_NODES * 4);
    int*   csr    = (int*)alloc((size_t)N_EDGES * 4);
    float* h1     = (float*)alloc((size_t)N_NODES * IN_F * 4);
    float* h2     = (float*)alloc((size_t)N_NODES * IN_F * 4);
    unsigned short* w1hi = (unsigned short*)alloc((size_t)HID_F * IN_F * 2);
    unsigned short* w1lo = (unsigned short*)alloc((size_t)HID_F * IN_F * 2);
    unsigned short* w2hi = (unsigned short*)alloc((size_t)CLS_P * HID_F * 2);
    unsigned short* w2lo = (unsigned short*)alloc((size_t)CLS_P * HID_F * 2);

    hipMemsetAsync(counts, 0, (size_t)N_NODES * 4, stream);

    int nb = (N_NODES + 255) / 256;   // 157
    k_count<<<(N_EDGES + 255) / 256, 256, 0, stream>>>(dst, counts);
    k_prep<<<(IN_F * HID_F + CLS_P * HID_F + 255) / 256, 256, 0, stream>>>(
        W1, W2, w1hi, w1lo, w2hi, w2lo);
    k_scan1<<<nb, 256, 0, stream>>>(counts, bsum);
    k_scan2<<<1, 64, 0, stream>>>(bsum, nb);
    k_scan3<<<nb, 256, 0, stream>>>(counts, bsum, rowptr, cursor);
    k_norm<<<nb, 256, 0, stream>>>(counts, norm, norm2);
    k_fill<<<(N_EDGES + 255) / 256, 256, 0, stream>>>(src, dst, cursor, csr);

    // hop1: scale by norm[src]; hop2: scale by norm^2[src]; trailing norm folded into MLP
    k_hop<<<(N_NODES + 7) / 8, 256, 0, stream>>>(features, h1, csr, rowptr, counts, norm);
    k_hop<<<(N_NODES + 7) / 8, 256, 0, stream>>>(h1, h2, csr, rowptr, counts, norm2);

    k_mlp<<<N_NODES / MB, 256, 0, stream>>>(h2, norm, w1hi, w1lo, b1, w2hi, w2lo, b2, out);
}

// Round 3
// 298.132 us; speedup vs baseline: 1.2276x; 1.1383x over previous
//
#include <hip/hip_runtime.h>

#define N_NODES 40000
#define N_EDGES 640000
#define IN_F 128
#define HID_F 256
#define CLS_F 40
#define CLS_P 48      // padded to 3 MFMA tiles of 16
#define MB 16         // nodes per block in fused MLP (16 -> 2500 blocks, high occupancy)
#define TS_LD 264     // ushort row stride for relu intermediate (bank spread)

typedef __attribute__((ext_vector_type(8))) short bf16x8;
typedef __attribute__((ext_vector_type(4))) float f32x4;

#define MFMA(a, b, c) __builtin_amdgcn_mfma_f32_16x16x32_bf16(a, b, c, 0, 0, 0)

__device__ __forceinline__ unsigned short f32_to_bf16_rne(float f) {
    unsigned int u = __float_as_uint(f);
    unsigned int r = u + 0x7fffu + ((u >> 16) & 1u);
    return (unsigned short)(r >> 16);
}

// ---------------- CSR build ----------------

__global__ void k_count(const int* __restrict__ dst, int* __restrict__ counts) {
    int e = blockIdx.x * blockDim.x + threadIdx.x;
    if (e < N_EDGES) atomicAdd(&counts[dst[e]], 1);
}

__global__ void k_scan1(const int* __restrict__ counts, int* __restrict__ bsum) {
    __shared__ int s[256];
    int i = blockIdx.x * 256 + threadIdx.x;
    s[threadIdx.x] = (i < N_NODES) ? counts[i] : 0;
    __syncthreads();
    for (int off = 128; off > 0; off >>= 1) {
        if (threadIdx.x < off) s[threadIdx.x] += s[threadIdx.x + off];
        __syncthreads();
    }
    if (threadIdx.x == 0) bsum[blockIdx.x] = s[0];
}

// parallel exclusive scan over <=256 block sums (157 used)
__global__ void k_scan2(int* __restrict__ bsum, int nb) {
    __shared__ int s[256];
    int t = threadIdx.x;
    int v = (t < nb) ? bsum[t] : 0;
    s[t] = v;
    __syncthreads();
    for (int off = 1; off < 256; off <<= 1) {
        int x = (t >= off) ? s[t - off] : 0;
        __syncthreads();
        s[t] += x;
        __syncthreads();
    }
    if (t < nb) bsum[t] = s[t] - v;   // exclusive
}

__global__ void k_scan3(const int* __restrict__ counts, const int* __restrict__ bsum,
                        int* __restrict__ rowptr, int* __restrict__ cursor) {
    __shared__ int s[256];
    int t = threadIdx.x;
    int i = blockIdx.x * 256 + t;
    int v = (i < N_NODES) ? counts[i] : 0;
    s[t] = v;
    __syncthreads();
    for (int off = 1; off < 256; off <<= 1) {
        int x = (t >= off) ? s[t - off] : 0;
        __syncthreads();
        s[t] += x;
        __syncthreads();
    }
    if (i < N_NODES) {
        int excl = s[t] - v + bsum[blockIdx.x];
        rowptr[i] = excl;
        cursor[i] = excl;
    }
}

__global__ void k_norm(const int* __restrict__ counts,
                       float* __restrict__ norm, float* __restrict__ norm2) {
    int i = blockIdx.x * blockDim.x + threadIdx.x;
    if (i < N_NODES) {
        float d = (float)counts[i];
        float r = rsqrtf(fmaxf(d, 1.0f));
        norm[i] = r;
        norm2[i] = r * r;
    }
}

__global__ void k_fill(const int* __restrict__ src, const int* __restrict__ dst,
                       int* __restrict__ cursor, int* __restrict__ csr_src) {
    int e = blockIdx.x * blockDim.x + threadIdx.x;
    if (e < N_EDGES) {
        int d = dst[e];
        int p = atomicAdd(&cursor[d], 1);
        csr_src[p] = src[e];
    }
}

// ---------------- weight prep: split fp32 -> bf16 hi/lo, transposed [col][k] ----------------

__global__ __launch_bounds__(256) void k_prep(
        const float* __restrict__ W1, const float* __restrict__ W2,
        unsigned short* __restrict__ w1hi, unsigned short* __restrict__ w1lo,
        unsigned short* __restrict__ w2hi, unsigned short* __restrict__ w2lo) {
    int idx = blockIdx.x * 256 + threadIdx.x;
    if (idx < IN_F * HID_F) {
        int k = idx >> 8;
        int c = idx & 255;
        float v = W1[idx];
        unsigned short hi = f32_to_bf16_rne(v);
        float fh = __uint_as_float((unsigned)hi << 16);
        unsigned short lo = f32_to_bf16_rne(v - fh);
        w1hi[c * IN_F + k] = hi;
        w1lo[c * IN_F + k] = lo;
    }
    int idx2 = idx - IN_F * HID_F;
    if (idx2 >= 0 && idx2 < CLS_P * HID_F) {
        int c = idx2 >> 8;
        int k = idx2 & 255;
        float v = (c < CLS_F) ? W2[k * CLS_F + c] : 0.f;
        unsigned short hi = f32_to_bf16_rne(v);
        float fh = __uint_as_float((unsigned)hi << 16);
        unsigned short lo = f32_to_bf16_rne(v - fh);
        w2hi[c * HID_F + k] = hi;
        w2lo[c * HID_F + k] = lo;
    }
}

// ---------------- propagation hop (gather, no atomics), 4-way edge unroll ----------------

__global__ __launch_bounds__(256) void k_hop(
        const float* __restrict__ gin, float* __restrict__ gout,
        const int* __restrict__ csr_src, const int* __restrict__ rowptr,
        const int* __restrict__ counts, const float* __restrict__ scale) {
    int gid  = blockIdx.x * 8 + (threadIdx.x >> 5);
    int lane = threadIdx.x & 31;
    if (gid >= N_NODES) return;
    int start = rowptr[gid];
    int cnt   = counts[gid];
    float4 acc = make_float4(0.f, 0.f, 0.f, 0.f);
    int i = 0;
    for (; i + 3 < cnt; i += 4) {
        int s0 = csr_src[start + i];
        int s1 = csr_src[start + i + 1];
        int s2 = csr_src[start + i + 2];
        int s3 = csr_src[start + i + 3];
        float c0 = scale[s0], c1 = scale[s1], c2 = scale[s2], c3 = scale[s3];
        float4 v0 = ((const float4*)(gin + (size_t)s0 * IN_F))[lane];
        float4 v1 = ((const float4*)(gin + (size_t)s1 * IN_F))[lane];
        float4 v2 = ((const float4*)(gin + (size_t)s2 * IN_F))[lane];
        float4 v3 = ((const float4*)(gin + (size_t)s3 * IN_F))[lane];
        acc.x = fmaf(v0.x, c0, acc.x); acc.y = fmaf(v0.y, c0, acc.y);
        acc.z = fmaf(v0.z, c0, acc.z); acc.w = fmaf(v0.w, c0, acc.w);
        acc.x = fmaf(v1.x, c1, acc.x); acc.y = fmaf(v1.y, c1, acc.y);
        acc.z = fmaf(v1.z, c1, acc.z); acc.w = fmaf(v1.w, c1, acc.w);
        acc.x = fmaf(v2.x, c2, acc.x); acc.y = fmaf(v2.y, c2, acc.y);
        acc.z = fmaf(v2.z, c2, acc.z); acc.w = fmaf(v2.w, c2, acc.w);
        acc.x = fmaf(v3.x, c3, acc.x); acc.y = fmaf(v3.y, c3, acc.y);
        acc.z = fmaf(v3.z, c3, acc.z); acc.w = fmaf(v3.w, c3, acc.w);
    }
    for (; i < cnt; i++) {
        int s = csr_src[start + i];
        float sc = scale[s];
        float4 v = ((const float4*)(gin + (size_t)s * IN_F))[lane];
        acc.x = fmaf(v.x, sc, acc.x); acc.y = fmaf(v.y, sc, acc.y);
        acc.z = fmaf(v.z, sc, acc.z); acc.w = fmaf(v.w, sc, acc.w);
    }
    ((float4*)(gout + (size_t)gid * IN_F))[lane] = acc;
}

// hop variant with fused trailing-norm + bf16 hi/lo split output (feeds MFMA MLP)
__global__ __launch_bounds__(256) void k_hop_split(
        const float* __restrict__ gin,
        unsigned short* __restrict__ ghi, unsigned short* __restrict__ glo,
        const int* __restrict__ csr_src, const int* __restrict__ rowptr,
        const int* __restrict__ counts, const float* __restrict__ scale,
        const float* __restrict__ norm) {
    int gid  = blockIdx.x * 8 + (threadIdx.x >> 5);
    int lane = threadIdx.x & 31;
    if (gid >= N_NODES) return;
    int start = rowptr[gid];
    int cnt   = counts[gid];
    float4 acc = make_float4(0.f, 0.f, 0.f, 0.f);
    int i = 0;
    for (; i + 3 < cnt; i += 4) {
        int s0 = csr_src[start + i];
        int s1 = csr_src[start + i + 1];
        int s2 = csr_src[start + i + 2];
        int s3 = csr_src[start + i + 3];
        float c0 = scale[s0], c1 = scale[s1], c2 = scale[s2], c3 = scale[s3];
        float4 v0 = ((const float4*)(gin + (size_t)s0 * IN_F))[lane];
        float4 v1 = ((const float4*)(gin + (size_t)s1 * IN_F))[lane];
        float4 v2 = ((const float4*)(gin + (size_t)s2 * IN_F))[lane];
        float4 v3 = ((const float4*)(gin + (size_t)s3 * IN_F))[lane];
        acc.x = fmaf(v0.x, c0, acc.x); acc.y = fmaf(v0.y, c0, acc.y);
        acc.z = fmaf(v0.z, c0, acc.z); acc.w = fmaf(v0.w, c0, acc.w);
        acc.x = fmaf(v1.x, c1, acc.x); acc.y = fmaf(v1.y, c1, acc.y);
        acc.z = fmaf(v1.z, c1, acc.z); acc.w = fmaf(v1.w, c1, acc.w);
        acc.x = fmaf(v2.x, c2, acc.x); acc.y = fmaf(v2.y, c2, acc.y);
        acc.z = fmaf(v2.z, c2, acc.z); acc.w = fmaf(v2.w, c2, acc.w);
        acc.x = fmaf(v3.x, c3, acc.x); acc.y = fmaf(v3.y, c3, acc.y);
        acc.z = fmaf(v3.z, c3, acc.z); acc.w = fmaf(v3.w, c3, acc.w);
    }
    for (; i < cnt; i++) {
        int s = csr_src[start + i];
        float sc = scale[s];
        float4 v = ((const float4*)(gin + (size_t)s * IN_F))[lane];
        acc.x = fmaf(v.x, sc, acc.x); acc.y = fmaf(v.y, sc, acc.y);
        acc.z = fmaf(v.z, sc, acc.z); acc.w = fmaf(v.w, sc, acc.w);
    }
    float nrm = norm[gid];
    float vv[4] = {acc.x * nrm, acc.y * nrm, acc.z * nrm, acc.w * nrm};
    ushort4 h, l;
    unsigned short* hp = (unsigned short*)&h;
    unsigned short* lp = (unsigned short*)&l;
    #pragma unroll
    for (int j = 0; j < 4; j++) {
        unsigned short hi = f32_to_bf16_rne(vv[j]);
        float fh = __uint_as_float((unsigned)hi << 16);
        hp[j] = hi;
        lp[j] = f32_to_bf16_rne(vv[j] - fh);
    }
    ((ushort4*)(ghi + (size_t)gid * IN_F))[lane] = h;
    ((ushort4*)(glo + (size_t)gid * IN_F))[lane] = l;
}

// ---------------- fused MLP via split-bf16 MFMA ----------------
// D = Ahi*Bhi + Ahi*Blo + Alo*Bhi  (fp32 accum).
// MB=16 rows/block, 4 waves split the 256 hidden cols (64 each) in GEMM1.
// A comes pre-split from k_hop_split (pure 16B loads, no conversion VALU).
// relu intermediate -> LDS hi/lo planes -> GEMM2 (3 col-tiles on waves 0-2).

__global__ __launch_bounds__(256, 6) void k_mlp(
        const unsigned short* __restrict__ h2hi, const unsigned short* __restrict__ h2lo,
        const unsigned short* __restrict__ w1hi, const unsigned short* __restrict__ w1lo,
        const float* __restrict__ b1,
        const unsigned short* __restrict__ w2hi, const unsigned short* __restrict__ w2lo,
        const float* __restrict__ b2,
        float* __restrict__ out) {
    __shared__ __align__(16) unsigned short tshi[MB * TS_LD];  // 8.25 KB
    __shared__ __align__(16) unsigned short tslo[MB * TS_LD];  // 8.25 KB
    int n0 = blockIdx.x * MB;
    int t  = threadIdx.x;
    int w  = t >> 6;
    int l  = t & 63;
    int lr = l & 15;     // A-row / B-col within tile
    int lg = l >> 4;     // k-group

    // ---- A fragments: rows n0..n0+15, pre-split bf16 (8 x 16B loads) ----
    const unsigned short* hrow = h2hi + (size_t)(n0 + lr) * IN_F + lg * 8;
    const unsigned short* lrow = h2lo + (size_t)(n0 + lr) * IN_F + lg * 8;
    bf16x8 ah[4], al[4];
    #pragma unroll
    for (int kq = 0; kq < 4; kq++) {
        ah[kq] = *(const bf16x8*)(hrow + kq * 32);
        al[kq] = *(const bf16x8*)(lrow + kq * 32);
    }

    // ---- GEMM1: wave w owns cols [w*64, w*64+64) : 4 col-tiles ----
    int colbase = w * 64;
    #pragma unroll
    for (int ct = 0; ct < 4; ct++) {
        int col = colbase + ct * 16 + lr;
        const unsigned short* bhp = w1hi + (size_t)col * IN_F + lg * 8;
        const unsigned short* blp = w1lo + (size_t)col * IN_F + lg * 8;
        f32x4 acc = {0.f, 0.f, 0.f, 0.f};
        #pragma unroll
        for (int kq = 0; kq < 4; kq++) {
            bf16x8 bh = *(const bf16x8*)(bhp + kq * 32);
            bf16x8 bl = *(const bf16x8*)(blp + kq * 32);
            acc = MFMA(ah[kq], bh, acc);
            acc = MFMA(ah[kq], bl, acc);
            acc = MFMA(al[kq], bh, acc);
        }
        float bias = b1[col];
        #pragma unroll
        for (int r = 0; r < 4; r++) {
            int row = lg * 4 + r;                  // C layout: row=(lane>>4)*4+reg
            float v = acc[r] + bias;
            v = v > 0.f ? v : 0.f;
            unsigned short hi = f32_to_bf16_rne(v);
            float fh = __uint_as_float((unsigned)hi << 16);
            unsigned short lo = f32_to_bf16_rne(v - fh);
            tshi[row * TS_LD + col] = hi;
            tslo[row * TS_LD + col] = lo;
        }
    }
    __syncthreads();

    // ---- GEMM2: 3 col-tiles of 16 classes on waves 0..2 ----
    if (w < 3) {
        int col = w * 16 + lr;                     // 0..47 (padded)
        const unsigned short* ahp = tshi + lr * TS_LD + lg * 8;
        const unsigned short* alp = tslo + lr * TS_LD + lg * 8;
        const unsigned short* bhp = w2hi + (size_t)col * HID_F + lg * 8;
        const unsigned short* blp = w2lo + (size_t)col * HID_F + lg * 8;
        f32x4 acc = {0.f, 0.f, 0.f, 0.f};
        #pragma unroll
        for (int kk = 0; kk < 8; kk++) {
            bf16x8 a_h = *(const bf16x8*)(ahp + kk * 32);
            bf16x8 a_l = *(const bf16x8*)(alp + kk * 32);
            bf16x8 b_h = *(const bf16x8*)(bhp + kk * 32);
            bf16x8 b_l = *(const bf16x8*)(blp + kk * 32);
            acc = MFMA(a_h, b_h, acc);
            acc = MFMA(a_h, b_l, acc);
            acc = MFMA(a_l, b_h, acc);
        }
        if (col < CLS_F) {
            float bias = b2[col];
            #pragma unroll
            for (int r = 0; r < 4; r++) {
                int mrow = n0 + lg * 4 + r;
                out[(size_t)mrow * CLS_F + col] = acc[r] + bias;
            }
        }
    }
}

// ---------------- launch ----------------

extern "C" void kernel_launch(void* const* d_in, const int* in_sizes, int n_in,
                              void* d_out, int out_size, void* d_ws, size_t ws_size,
                              hipStream_t stream) {
    const float* features = (const float*)d_in[0];
    const int*   src      = (const int*)d_in[1];
    const int*   dst      = (const int*)d_in[2];
    const float* W1       = (const float*)d_in[3];
    const float* b1       = (const float*)d_in[4];
    const float* W2       = (const float*)d_in[5];
    const float* b2       = (const float*)d_in[6];
    float*       out      = (float*)d_out;

    char* ws = (char*)d_ws;
    size_t off = 0;
    auto alloc = [&](size_t bytes) -> void* {
        void* p = ws + off;
        off += (bytes + 255) & ~(size_t)255;
        return p;
    };
    int*   counts = (int*)alloc((size_t)N_NODES * 4);
    int*   rowptr = (int*)alloc((size_t)N_NODES * 4);
    int*   cursor = (int*)alloc((size_t)N_NODES * 4);
    int*   bsum   = (int*)alloc(256 * 4);
    float* norm   = (float*)alloc((size_t)N_NODES * 4);
    float* norm2  = (float*)alloc((size_t)N_NODES * 4);
    int*   csr    = (int*)alloc((size_t)N_EDGES * 4);
    float* h1     = (float*)alloc((size_t)N_NODES * IN_F * 4);
    unsigned short* h2hi = (unsigned short*)alloc((size_t)N_NODES * IN_F * 2);
    unsigned short* h2lo = (unsigned short*)alloc((size_t)N_NODES * IN_F * 2);
    unsigned short* w1hi = (unsigned short*)alloc((size_t)HID_F * IN_F * 2);
    unsigned short* w1lo = (unsigned short*)alloc((size_t)HID_F * IN_F * 2);
    unsigned short* w2hi = (unsigned short*)alloc((size_t)CLS_P * HID_F * 2);
    unsigned short* w2lo = (unsigned short*)alloc((size_t)CLS_P * HID_F * 2);

    hipMemsetAsync(counts, 0, (size_t)N_NODES * 4, stream);

    int nb = (N_NODES + 255) / 256;   // 157
    k_count<<<(N_EDGES + 255) / 256, 256, 0, stream>>>(dst, counts);
    k_prep<<<(IN_F * HID_F + CLS_P * HID_F + 255) / 256, 256, 0, stream>>>(
        W1, W2, w1hi, w1lo, w2hi, w2lo);
    k_scan1<<<nb, 256, 0, stream>>>(counts, bsum);
    k_scan2<<<1, 256, 0, stream>>>(bsum, nb);
    k_scan3<<<nb, 256, 0, stream>>>(counts, bsum, rowptr, cursor);
    k_norm<<<nb, 256, 0, stream>>>(counts, norm, norm2);
    k_fill<<<(N_EDGES + 255) / 256, 256, 0, stream>>>(src, dst, cursor, csr);

    // hop1: scale by norm[src]; hop2: scale by norm^2[src], trailing norm + bf16 split fused
    k_hop<<<(N_NODES + 7) / 8, 256, 0, stream>>>(features, h1, csr, rowptr, counts, norm);
    k_hop_split<<<(N_NODES + 7) / 8, 256, 0, stream>>>(h1, h2hi, h2lo, csr, rowptr, counts,
                                                       norm2, norm);

    k_mlp<<<N_NODES / MB, 256, 0, stream>>>(h2hi, h2lo, w1hi, w1lo, b1, w2hi, w2lo, b2, out);
}

// Round 5
// 270.690 us; speedup vs baseline: 1.3520x; 1.1014x over previous
//
#include <hip/hip_runtime.h>

#define N_NODES 40000
#define N_EDGES 640000
#define IN_F 128
#define HID_F 256
#define CLS_F 40
#define CLS_P 48      // padded to 3 MFMA tiles of 16
#define MB 32         // nodes per block in fused MLP (2 row-tiles of 16; 1250 blocks)
#define TS_LD 264     // ushort row stride: MUST be >= 256 (row width); 528B, 16B-aligned

typedef __attribute__((ext_vector_type(8))) short bf16x8;
typedef __attribute__((ext_vector_type(4))) float f32x4;

#define MFMA(a, b, c) __builtin_amdgcn_mfma_f32_16x16x32_bf16(a, b, c, 0, 0, 0)

__device__ __forceinline__ unsigned short f32_to_bf16_rne(float f) {
    unsigned int u = __float_as_uint(f);
    unsigned int r = u + 0x7fffu + ((u >> 16) & 1u);
    return (unsigned short)(r >> 16);
}

// ---------------- CSR build ----------------

__global__ void k_count(const int* __restrict__ dst, int* __restrict__ counts) {
    int e = blockIdx.x * blockDim.x + threadIdx.x;
    if (e < N_EDGES) atomicAdd(&counts[dst[e]], 1);
}

__global__ void k_scan1(const int* __restrict__ counts, int* __restrict__ bsum) {
    __shared__ int s[256];
    int i = blockIdx.x * 256 + threadIdx.x;
    s[threadIdx.x] = (i < N_NODES) ? counts[i] : 0;
    __syncthreads();
    for (int off = 128; off > 0; off >>= 1) {
        if (threadIdx.x < off) s[threadIdx.x] += s[threadIdx.x + off];
        __syncthreads();
    }
    if (threadIdx.x == 0) bsum[blockIdx.x] = s[0];
}

// parallel exclusive scan over <=256 block sums (157 used)
__global__ void k_scan2(int* __restrict__ bsum, int nb) {
    __shared__ int s[256];
    int t = threadIdx.x;
    int v = (t < nb) ? bsum[t] : 0;
    s[t] = v;
    __syncthreads();
    for (int off = 1; off < 256; off <<= 1) {
        int x = (t >= off) ? s[t - off] : 0;
        __syncthreads();
        s[t] += x;
        __syncthreads();
    }
    if (t < nb) bsum[t] = s[t] - v;   // exclusive
}

__global__ void k_scan3(const int* __restrict__ counts, const int* __restrict__ bsum,
                        int* __restrict__ rowptr, int* __restrict__ cursor) {
    __shared__ int s[256];
    int t = threadIdx.x;
    int i = blockIdx.x * 256 + t;
    int v = (i < N_NODES) ? counts[i] : 0;
    s[t] = v;
    __syncthreads();
    for (int off = 1; off < 256; off <<= 1) {
        int x = (t >= off) ? s[t - off] : 0;
        __syncthreads();
        s[t] += x;
        __syncthreads();
    }
    if (i < N_NODES) {
        int excl = s[t] - v + bsum[blockIdx.x];
        rowptr[i] = excl;
        cursor[i] = excl;
    }
}

__global__ void k_norm(const int* __restrict__ counts,
                       float* __restrict__ norm, float* __restrict__ norm2) {
    int i = blockIdx.x * blockDim.x + threadIdx.x;
    if (i < N_NODES) {
        float d = (float)counts[i];
        float r = rsqrtf(fmaxf(d, 1.0f));
        norm[i] = r;
        norm2[i] = r * r;
    }
}

__global__ void k_fill(const int* __restrict__ src, const int* __restrict__ dst,
                       int* __restrict__ cursor, int* __restrict__ csr_src) {
    int e = blockIdx.x * blockDim.x + threadIdx.x;
    if (e < N_EDGES) {
        int d = dst[e];
        int p = atomicAdd(&cursor[d], 1);
        csr_src[p] = src[e];
    }
}

// ---------------- weight prep: split fp32 -> bf16 hi/lo, transposed [col][k] ----------------

__global__ __launch_bounds__(256) void k_prep(
        const float* __restrict__ W1, const float* __restrict__ W2,
        unsigned short* __restrict__ w1hi, unsigned short* __restrict__ w1lo,
        unsigned short* __restrict__ w2hi, unsigned short* __restrict__ w2lo) {
    int idx = blockIdx.x * 256 + threadIdx.x;
    if (idx < IN_F * HID_F) {
        int k = idx >> 8;
        int c = idx & 255;
        float v = W1[idx];
        unsigned short hi = f32_to_bf16_rne(v);
        float fh = __uint_as_float((unsigned)hi << 16);
        unsigned short lo = f32_to_bf16_rne(v - fh);
        w1hi[c * IN_F + k] = hi;
        w1lo[c * IN_F + k] = lo;
    }
    int idx2 = idx - IN_F * HID_F;
    if (idx2 >= 0 && idx2 < CLS_P * HID_F) {
        int c = idx2 >> 8;
        int k = idx2 & 255;
        float v = (c < CLS_F) ? W2[k * CLS_F + c] : 0.f;
        unsigned short hi = f32_to_bf16_rne(v);
        float fh = __uint_as_float((unsigned)hi << 16);
        unsigned short lo = f32_to_bf16_rne(v - fh);
        w2hi[c * HID_F + k] = hi;
        w2lo[c * HID_F + k] = lo;
    }
}

// ---------------- propagation hop (gather, no atomics), 4-way edge unroll ----------------

__global__ __launch_bounds__(256) void k_hop(
        const float* __restrict__ gin, float* __restrict__ gout,
        const int* __restrict__ csr_src, const int* __restrict__ rowptr,
        const int* __restrict__ counts, const float* __restrict__ scale) {
    int gid  = blockIdx.x * 8 + (threadIdx.x >> 5);
    int lane = threadIdx.x & 31;
    if (gid >= N_NODES) return;
    int start = rowptr[gid];
    int cnt   = counts[gid];
    float4 acc = make_float4(0.f, 0.f, 0.f, 0.f);
    int i = 0;
    for (; i + 3 < cnt; i += 4) {
        int s0 = csr_src[start + i];
        int s1 = csr_src[start + i + 1];
        int s2 = csr_src[start + i + 2];
        int s3 = csr_src[start + i + 3];
        float c0 = scale[s0], c1 = scale[s1], c2 = scale[s2], c3 = scale[s3];
        float4 v0 = ((const float4*)(gin + (size_t)s0 * IN_F))[lane];
        float4 v1 = ((const float4*)(gin + (size_t)s1 * IN_F))[lane];
        float4 v2 = ((const float4*)(gin + (size_t)s2 * IN_F))[lane];
        float4 v3 = ((const float4*)(gin + (size_t)s3 * IN_F))[lane];
        acc.x = fmaf(v0.x, c0, acc.x); acc.y = fmaf(v0.y, c0, acc.y);
        acc.z = fmaf(v0.z, c0, acc.z); acc.w = fmaf(v0.w, c0, acc.w);
        acc.x = fmaf(v1.x, c1, acc.x); acc.y = fmaf(v1.y, c1, acc.y);
        acc.z = fmaf(v1.z, c1, acc.z); acc.w = fmaf(v1.w, c1, acc.w);
        acc.x = fmaf(v2.x, c2, acc.x); acc.y = fmaf(v2.y, c2, acc.y);
        acc.z = fmaf(v2.z, c2, acc.z); acc.w = fmaf(v2.w, c2, acc.w);
        acc.x = fmaf(v3.x, c3, acc.x); acc.y = fmaf(v3.y, c3, acc.y);
        acc.z = fmaf(v3.z, c3, acc.z); acc.w = fmaf(v3.w, c3, acc.w);
    }
    for (; i < cnt; i++) {
        int s = csr_src[start + i];
        float sc = scale[s];
        float4 v = ((const float4*)(gin + (size_t)s * IN_F))[lane];
        acc.x = fmaf(v.x, sc, acc.x); acc.y = fmaf(v.y, sc, acc.y);
        acc.z = fmaf(v.z, sc, acc.z); acc.w = fmaf(v.w, sc, acc.w);
    }
    ((float4*)(gout + (size_t)gid * IN_F))[lane] = acc;
}

// hop variant with fused trailing-norm + bf16 hi/lo split output (feeds MFMA MLP)
__global__ __launch_bounds__(256) void k_hop_split(
        const float* __restrict__ gin,
        unsigned short* __restrict__ ghi, unsigned short* __restrict__ glo,
        const int* __restrict__ csr_src, const int* __restrict__ rowptr,
        const int* __restrict__ counts, const float* __restrict__ scale,
        const float* __restrict__ norm) {
    int gid  = blockIdx.x * 8 + (threadIdx.x >> 5);
    int lane = threadIdx.x & 31;
    if (gid >= N_NODES) return;
    int start = rowptr[gid];
    int cnt   = counts[gid];
    float4 acc = make_float4(0.f, 0.f, 0.f, 0.f);
    int i = 0;
    for (; i + 3 < cnt; i += 4) {
        int s0 = csr_src[start + i];
        int s1 = csr_src[start + i + 1];
        int s2 = csr_src[start + i + 2];
        int s3 = csr_src[start + i + 3];
        float c0 = scale[s0], c1 = scale[s1], c2 = scale[s2], c3 = scale[s3];
        float4 v0 = ((const float4*)(gin + (size_t)s0 * IN_F))[lane];
        float4 v1 = ((const float4*)(gin + (size_t)s1 * IN_F))[lane];
        float4 v2 = ((const float4*)(gin + (size_t)s2 * IN_F))[lane];
        float4 v3 = ((const float4*)(gin + (size_t)s3 * IN_F))[lane];
        acc.x = fmaf(v0.x, c0, acc.x); acc.y = fmaf(v0.y, c0, acc.y);
        acc.z = fmaf(v0.z, c0, acc.z); acc.w = fmaf(v0.w, c0, acc.w);
        acc.x = fmaf(v1.x, c1, acc.x); acc.y = fmaf(v1.y, c1, acc.y);
        acc.z = fmaf(v1.z, c1, acc.z); acc.w = fmaf(v1.w, c1, acc.w);
        acc.x = fmaf(v2.x, c2, acc.x); acc.y = fmaf(v2.y, c2, acc.y);
        acc.z = fmaf(v2.z, c2, acc.z); acc.w = fmaf(v2.w, c2, acc.w);
        acc.x = fmaf(v3.x, c3, acc.x); acc.y = fmaf(v3.y, c3, acc.y);
        acc.z = fmaf(v3.z, c3, acc.z); acc.w = fmaf(v3.w, c3, acc.w);
    }
    for (; i < cnt; i++) {
        int s = csr_src[start + i];
        float sc = scale[s];
        float4 v = ((const float4*)(gin + (size_t)s * IN_F))[lane];
        acc.x = fmaf(v.x, sc, acc.x); acc.y = fmaf(v.y, sc, acc.y);
        acc.z = fmaf(v.z, sc, acc.z); acc.w = fmaf(v.w, sc, acc.w);
    }
    float nrm = norm[gid];
    float vv[4] = {acc.x * nrm, acc.y * nrm, acc.z * nrm, acc.w * nrm};
    ushort4 h, l;
    unsigned short* hp = (unsigned short*)&h;
    unsigned short* lp = (unsigned short*)&l;
    #pragma unroll
    for (int j = 0; j < 4; j++) {
        unsigned short hi = f32_to_bf16_rne(vv[j]);
        float fh = __uint_as_float((unsigned)hi << 16);
        hp[j] = hi;
        lp[j] = f32_to_bf16_rne(vv[j] - fh);
    }
    ((ushort4*)(ghi + (size_t)gid * IN_F))[lane] = h;
    ((ushort4*)(glo + (size_t)gid * IN_F))[lane] = l;
}

// ---------------- fused MLP via split-bf16 MFMA, weights-in-registers ----------------
// D = Ahi*Bhi + Ahi*Blo + Alo*Bhi (fp32 accum).
// Block: 4 waves, MB=32 rows (2 row-tiles of 16). Wave w owns GEMM1 cols
// [w*64, w*64+64): its 32 W1 fragments (128 VGPR) are preloaded ONCE, then the
// 2 row-tiles stream through with A double-buffered. GEMM2: waves 0-2 each own
// one 16-class col-tile with 16 W2 fragments (64 VGPR) preloaded.

#define LOAD_A(AH, AL, rt) do {                                              \
    const unsigned short* hp_ = h2hi + (size_t)(n0 + (rt) * 16 + lr) * IN_F + lg * 8; \
    const unsigned short* lp_ = h2lo + (size_t)(n0 + (rt) * 16 + lr) * IN_F + lg * 8; \
    _Pragma("unroll")                                                        \
    for (int kq = 0; kq < 4; kq++) {                                         \
        AH[kq] = *(const bf16x8*)(hp_ + kq * 32);                            \
        AL[kq] = *(const bf16x8*)(lp_ + kq * 32);                            \
    }                                                                        \
} while (0)

#define TILE(AH, AL, rt) do {                                                \
    _Pragma("unroll")                                                        \
    for (int ct = 0; ct < 4; ct++) {                                         \
        f32x4 acc = {0.f, 0.f, 0.f, 0.f};                                    \
        _Pragma("unroll")                                                    \
        for (int kq = 0; kq < 4; kq++) {                                     \
            acc = MFMA(AH[kq], b1h[ct][kq], acc);                            \
            acc = MFMA(AH[kq], b1l[ct][kq], acc);                            \
            acc = MFMA(AL[kq], b1h[ct][kq], acc);                            \
        }                                                                    \
        int col_ = w * 64 + ct * 16 + lr;                                    \
        _Pragma("unroll")                                                    \
        for (int r = 0; r < 4; r++) {                                        \
            int row_ = (rt) * 16 + lg * 4 + r;                               \
            float v_ = acc[r] + b1v[ct];                                     \
            v_ = v_ > 0.f ? v_ : 0.f;                                        \
            unsigned short hi_ = f32_to_bf16_rne(v_);                        \
            float fh_ = __uint_as_float((unsigned)hi_ << 16);                \
            tshi[row_ * TS_LD + col_] = hi_;                                 \
            tslo[row_ * TS_LD + col_] = f32_to_bf16_rne(v_ - fh_);           \
        }                                                                    \
    }                                                                        \
} while (0)

__global__ __launch_bounds__(256, 2) void k_mlp(
        const unsigned short* __restrict__ h2hi, const unsigned short* __restrict__ h2lo,
        const unsigned short* __restrict__ w1hi, const unsigned short* __restrict__ w1lo,
        const float* __restrict__ b1,
        const unsigned short* __restrict__ w2hi, const unsigned short* __restrict__ w2lo,
        const float* __restrict__ b2,
        float* __restrict__ out) {
    __shared__ __align__(16) unsigned short tshi[MB * TS_LD];  // 16.5 KB
    __shared__ __align__(16) unsigned short tslo[MB * TS_LD];  // 16.5 KB
    int n0 = blockIdx.x * MB;
    int t  = threadIdx.x;
    int w  = t >> 6;
    int l  = t & 63;
    int lr = l & 15;     // A-row / B-col within tile
    int lg = l >> 4;     // k-group

    // ---- preload W1 fragments for this wave's 64 cols: 32 frags = 128 VGPR ----
    bf16x8 b1h[4][4], b1l[4][4];
    float  b1v[4];
    #pragma unroll
    for (int ct = 0; ct < 4; ct++) {
        int col = w * 64 + ct * 16 + lr;
        const unsigned short* bhp = w1hi + (size_t)col * IN_F + lg * 8;
        const unsigned short* blp = w1lo + (size_t)col * IN_F + lg * 8;
        #pragma unroll
        for (int kq = 0; kq < 4; kq++) {
            b1h[ct][kq] = *(const bf16x8*)(bhp + kq * 32);
            b1l[ct][kq] = *(const bf16x8*)(blp + kq * 32);
        }
        b1v[ct] = b1[col];
    }

    // ---- GEMM1 over 2 row-tiles, A double-buffered ----
    bf16x8 aAh[4], aAl[4], aBh[4], aBl[4];
    LOAD_A(aAh, aAl, 0);
    LOAD_A(aBh, aBl, 1);
    TILE(aAh, aAl, 0);
    TILE(aBh, aBl, 1);
    __syncthreads();

    // ---- GEMM2: waves 0-2, one 16-class col-tile each, W2 frags in regs ----
    if (w < 3) {
        int col = w * 16 + lr;                     // 0..47 (padded)
        bf16x8 b2h[8], b2l[8];
        const unsigned short* bhp = w2hi + (size_t)col * HID_F + lg * 8;
        const unsigned short* blp = w2lo + (size_t)col * HID_F + lg * 8;
        #pragma unroll
        for (int kk = 0; kk < 8; kk++) {
            b2h[kk] = *(const bf16x8*)(bhp + kk * 32);
            b2l[kk] = *(const bf16x8*)(blp + kk * 32);
        }
        float bias = (col < CLS_F) ? b2[col] : 0.f;
        #pragma unroll
        for (int rt2 = 0; rt2 < 2; rt2++) {
            const unsigned short* ahp = tshi + (rt2 * 16 + lr) * TS_LD + lg * 8;
            const unsigned short* alp = tslo + (rt2 * 16 + lr) * TS_LD + lg * 8;
            f32x4 acc0 = {0.f, 0.f, 0.f, 0.f};
            f32x4 acc1 = {0.f, 0.f, 0.f, 0.f};
            #pragma unroll
            for (int kk = 0; kk < 4; kk++) {
                bf16x8 a_h0 = *(const bf16x8*)(ahp + kk * 32);
                bf16x8 a_l0 = *(const bf16x8*)(alp + kk * 32);
                bf16x8 a_h1 = *(const bf16x8*)(ahp + (kk + 4) * 32);
                bf16x8 a_l1 = *(const bf16x8*)(alp + (kk + 4) * 32);
                acc0 = MFMA(a_h0, b2h[kk], acc0);
                acc1 = MFMA(a_h1, b2h[kk + 4], acc1);
                acc0 = MFMA(a_h0, b2l[kk], acc0);
                acc1 = MFMA(a_h1, b2l[kk + 4], acc1);
                acc0 = MFMA(a_l0, b2h[kk], acc0);
                acc1 = MFMA(a_l1, b2h[kk + 4], acc1);
            }
            if (col < CLS_F) {
                #pragma unroll
                for (int r = 0; r < 4; r++) {
                    int mrow = n0 + rt2 * 16 + lg * 4 + r;
                    out[(size_t)mrow * CLS_F + col] = acc0[r] + acc1[r] + bias;
                }
            }
        }
    }
}

// ---------------- launch ----------------

extern "C" void kernel_launch(void* const* d_in, const int* in_sizes, int n_in,
                              void* d_out, int out_size, void* d_ws, size_t ws_size,
                              hipStream_t stream) {
    const float* features = (const float*)d_in[0];
    const int*   src      = (const int*)d_in[1];
    const int*   dst      = (const int*)d_in[2];
    const float* W1       = (const float*)d_in[3];
    const float* b1       = (const float*)d_in[4];
    const float* W2       = (const float*)d_in[5];
    const float* b2       = (const float*)d_in[6];
    float*       out      = (float*)d_out;

    char* ws = (char*)d_ws;
    size_t off = 0;
    auto alloc = [&](size_t bytes) -> void* {
        void* p = ws + off;
        off += (bytes + 255) & ~(size_t)255;
        return p;
    };
    int*   counts = (int*)alloc((size_t)N_NODES * 4);
    int*   rowptr = (int*)alloc((size_t)N_NODES * 4);
    int*   cursor = (int*)alloc((size_t)N_NODES * 4);
    int*   bsum   = (int*)alloc(256 * 4);
    float* norm   = (float*)alloc((size_t)N_NODES * 4);
    float* norm2  = (float*)alloc((size_t)N_NODES * 4);
    int*   csr    = (int*)alloc((size_t)N_EDGES * 4);
    float* h1     = (float*)alloc((size_t)N_NODES * IN_F * 4);
    unsigned short* h2hi = (unsigned short*)alloc((size_t)N_NODES * IN_F * 2);
    unsigned short* h2lo = (unsigned short*)alloc((size_t)N_NODES * IN_F * 2);
    unsigned short* w1hi = (unsigned short*)alloc((size_t)HID_F * IN_F * 2);
    unsigned short* w1lo = (unsigned short*)alloc((size_t)HID_F * IN_F * 2);
    unsigned short* w2hi = (unsigned short*)alloc((size_t)CLS_P * HID_F * 2);
    unsigned short* w2lo = (unsigned short*)alloc((size_t)CLS_P * HID_F * 2);

    hipMemsetAsync(counts, 0, (size_t)N_NODES * 4, stream);

    int nb = (N_NODES + 255) / 256;   // 157
    k_count<<<(N_EDGES + 255) / 256, 256, 0, stream>>>(dst, counts);
    k_prep<<<(IN_F * HID_F + CLS_P * HID_F + 255) / 256, 256, 0, stream>>>(
        W1, W2, w1hi, w1lo, w2hi, w2lo);
    k_scan1<<<nb, 256, 0, stream>>>(counts, bsum);
    k_scan2<<<1, 256, 0, stream>>>(bsum, nb);
    k_scan3<<<nb, 256, 0, stream>>>(counts, bsum, rowptr, cursor);
    k_norm<<<nb, 256, 0, stream>>>(counts, norm, norm2);
    k_fill<<<(N_EDGES + 255) / 256, 256, 0, stream>>>(src, dst, cursor, csr);

    // hop1: scale by norm[src]; hop2: scale by norm^2[src], trailing norm + bf16 split fused
    k_hop<<<(N_NODES + 7) / 8, 256, 0, stream>>>(features, h1, csr, rowptr, counts, norm);
    k_hop_split<<<(N_NODES + 7) / 8, 256, 0, stream>>>(h1, h2hi, h2lo, csr, rowptr, counts,
                                                       norm2, norm);

    k_mlp<<<N_NODES / MB, 256, 0, stream>>>(h2hi, h2lo, w1hi, w1lo, b1, w2hi, w2lo, b2, out);
}

// Round 6
// 269.221 us; speedup vs baseline: 1.3594x; 1.0055x over previous
//
#include <hip/hip_runtime.h>

#define N_NODES 40000
#define N_EDGES 640000
#define IN_F 128
#define HID_F 256
#define CLS_F 40
#define CLS_P 48      // padded to 3 MFMA tiles of 16
#define MB 32         // nodes per block in fused MLP (2 row-tiles of 16; 1250 blocks)
#define TS_LD 264     // ushort row stride: MUST be >= 256 (row width); 528B, 16B-aligned

typedef __attribute__((ext_vector_type(8))) short bf16x8;
typedef __attribute__((ext_vector_type(4))) float f32x4;

#define MFMA(a, b, c) __builtin_amdgcn_mfma_f32_16x16x32_bf16(a, b, c, 0, 0, 0)

__device__ __forceinline__ unsigned short f32_to_bf16_rne(float f) {
    unsigned int u = __float_as_uint(f);
    unsigned int r = u + 0x7fffu + ((u >> 16) & 1u);
    return (unsigned short)(r >> 16);
}

// ---------------- CSR build ----------------

__global__ void k_count(const int* __restrict__ dst, int* __restrict__ counts) {
    int e = blockIdx.x * blockDim.x + threadIdx.x;
    if (e < N_EDGES) atomicAdd(&counts[dst[e]], 1);
}

__global__ void k_scan1(const int* __restrict__ counts, int* __restrict__ bsum) {
    __shared__ int s[256];
    int i = blockIdx.x * 256 + threadIdx.x;
    s[threadIdx.x] = (i < N_NODES) ? counts[i] : 0;
    __syncthreads();
    for (int off = 128; off > 0; off >>= 1) {
        if (threadIdx.x < off) s[threadIdx.x] += s[threadIdx.x + off];
        __syncthreads();
    }
    if (threadIdx.x == 0) bsum[blockIdx.x] = s[0];
}

// parallel exclusive scan over <=256 block sums (157 used)
__global__ void k_scan2(int* __restrict__ bsum, int nb) {
    __shared__ int s[256];
    int t = threadIdx.x;
    int v = (t < nb) ? bsum[t] : 0;
    s[t] = v;
    __syncthreads();
    for (int off = 1; off < 256; off <<= 1) {
        int x = (t >= off) ? s[t - off] : 0;
        __syncthreads();
        s[t] += x;
        __syncthreads();
    }
    if (t < nb) bsum[t] = s[t] - v;   // exclusive
}

__global__ void k_scan3(const int* __restrict__ counts, const int* __restrict__ bsum,
                        int* __restrict__ rowptr, int* __restrict__ cursor) {
    __shared__ int s[256];
    int t = threadIdx.x;
    int i = blockIdx.x * 256 + t;
    int v = (i < N_NODES) ? counts[i] : 0;
    s[t] = v;
    __syncthreads();
    for (int off = 1; off < 256; off <<= 1) {
        int x = (t >= off) ? s[t - off] : 0;
        __syncthreads();
        s[t] += x;
        __syncthreads();
    }
    if (i < N_NODES) {
        int excl = s[t] - v + bsum[blockIdx.x];
        rowptr[i] = excl;
        cursor[i] = excl;
    }
}

__global__ void k_norm(const int* __restrict__ counts,
                       float* __restrict__ norm, float* __restrict__ norm2) {
    int i = blockIdx.x * blockDim.x + threadIdx.x;
    if (i < N_NODES) {
        float d = (float)counts[i];
        float r = rsqrtf(fmaxf(d, 1.0f));
        norm[i] = r;
        norm2[i] = r * r;
    }
}

__global__ void k_fill(const int* __restrict__ src, const int* __restrict__ dst,
                       int* __restrict__ cursor, int* __restrict__ csr_src) {
    int e = blockIdx.x * blockDim.x + threadIdx.x;
    if (e < N_EDGES) {
        int d = dst[e];
        int p = atomicAdd(&cursor[d], 1);
        csr_src[p] = src[e];
    }
}

// ---------------- weight prep: split fp32 -> bf16 hi/lo, transposed [col][k] ----------------

__global__ __launch_bounds__(256) void k_prep(
        const float* __restrict__ W1, const float* __restrict__ W2,
        unsigned short* __restrict__ w1hi, unsigned short* __restrict__ w1lo,
        unsigned short* __restrict__ w2hi, unsigned short* __restrict__ w2lo) {
    int idx = blockIdx.x * 256 + threadIdx.x;
    if (idx < IN_F * HID_F) {
        int k = idx >> 8;
        int c = idx & 255;
        float v = W1[idx];
        unsigned short hi = f32_to_bf16_rne(v);
        float fh = __uint_as_float((unsigned)hi << 16);
        unsigned short lo = f32_to_bf16_rne(v - fh);
        w1hi[c * IN_F + k] = hi;
        w1lo[c * IN_F + k] = lo;
    }
    int idx2 = idx - IN_F * HID_F;
    if (idx2 >= 0 && idx2 < CLS_P * HID_F) {
        int c = idx2 >> 8;
        int k = idx2 & 255;
        float v = (c < CLS_F) ? W2[k * CLS_F + c] : 0.f;
        unsigned short hi = f32_to_bf16_rne(v);
        float fh = __uint_as_float((unsigned)hi << 16);
        unsigned short lo = f32_to_bf16_rne(v - fh);
        w2hi[c * HID_F + k] = hi;
        w2lo[c * HID_F + k] = lo;
    }
}

// ---------------- propagation hop (gather, no atomics) ----------------
// 32 lanes per node, float4 per lane. Index loads software-pipelined one
// 4-edge batch ahead: while batch i's rows are in flight, batch i+1's
// indices are already loading (collapses the idx->row dependent chain).

#define HOP_BODY(S0, S1, S2, S3)                                             \
    do {                                                                     \
        float c0 = scale[S0], c1 = scale[S1], c2 = scale[S2], c3 = scale[S3];\
        float4 v0 = ((const float4*)(gin + (size_t)(S0) * IN_F))[lane];      \
        float4 v1 = ((const float4*)(gin + (size_t)(S1) * IN_F))[lane];      \
        float4 v2 = ((const float4*)(gin + (size_t)(S2) * IN_F))[lane];      \
        float4 v3 = ((const float4*)(gin + (size_t)(S3) * IN_F))[lane];      \
        acc.x = fmaf(v0.x, c0, acc.x); acc.y = fmaf(v0.y, c0, acc.y);        \
        acc.z = fmaf(v0.z, c0, acc.z); acc.w = fmaf(v0.w, c0, acc.w);        \
        acc.x = fmaf(v1.x, c1, acc.x); acc.y = fmaf(v1.y, c1, acc.y);        \
        acc.z = fmaf(v1.z, c1, acc.z); acc.w = fmaf(v1.w, c1, acc.w);        \
        acc.x = fmaf(v2.x, c2, acc.x); acc.y = fmaf(v2.y, c2, acc.y);        \
        acc.z = fmaf(v2.z, c2, acc.z); acc.w = fmaf(v2.w, c2, acc.w);        \
        acc.x = fmaf(v3.x, c3, acc.x); acc.y = fmaf(v3.y, c3, acc.y);        \
        acc.z = fmaf(v3.z, c3, acc.z); acc.w = fmaf(v3.w, c3, acc.w);        \
    } while (0)

#define HOP_GATHER                                                           \
    float4 acc = make_float4(0.f, 0.f, 0.f, 0.f);                            \
    int i = 0;                                                               \
    int n0i = 0, n1i = 0, n2i = 0, n3i = 0;                                  \
    if (cnt >= 4) {                                                          \
        n0i = csr_src[start];     n1i = csr_src[start + 1];                  \
        n2i = csr_src[start + 2]; n3i = csr_src[start + 3];                  \
    }                                                                        \
    for (; i + 7 < cnt; i += 4) {                                            \
        int s0 = n0i, s1 = n1i, s2 = n2i, s3 = n3i;                          \
        n0i = csr_src[start + i + 4]; n1i = csr_src[start + i + 5];          \
        n2i = csr_src[start + i + 6]; n3i = csr_src[start + i + 7];          \
        HOP_BODY(s0, s1, s2, s3);                                            \
    }                                                                        \
    if (i + 3 < cnt) {  /* consume the prefetched batch */                   \
        HOP_BODY(n0i, n1i, n2i, n3i);                                        \
        i += 4;                                                              \
    }                                                                        \
    for (; i < cnt; i++) {                                                   \
        int s = csr_src[start + i];                                          \
        float sc = scale[s];                                                 \
        float4 v = ((const float4*)(gin + (size_t)s * IN_F))[lane];          \
        acc.x = fmaf(v.x, sc, acc.x); acc.y = fmaf(v.y, sc, acc.y);          \
        acc.z = fmaf(v.z, sc, acc.z); acc.w = fmaf(v.w, sc, acc.w);          \
    }

__global__ __launch_bounds__(256) void k_hop(
        const float* __restrict__ gin, float* __restrict__ gout,
        const int* __restrict__ csr_src, const int* __restrict__ rowptr,
        const int* __restrict__ counts, const float* __restrict__ scale) {
    int gid  = blockIdx.x * 8 + (threadIdx.x >> 5);
    int lane = threadIdx.x & 31;
    if (gid >= N_NODES) return;
    int start = rowptr[gid];
    int cnt   = counts[gid];
    HOP_GATHER
    ((float4*)(gout + (size_t)gid * IN_F))[lane] = acc;
}

// hop variant with fused trailing-norm + bf16 hi/lo split output (feeds MFMA MLP)
__global__ __launch_bounds__(256) void k_hop_split(
        const float* __restrict__ gin,
        unsigned short* __restrict__ ghi, unsigned short* __restrict__ glo,
        const int* __restrict__ csr_src, const int* __restrict__ rowptr,
        const int* __restrict__ counts, const float* __restrict__ scale,
        const float* __restrict__ norm) {
    int gid  = blockIdx.x * 8 + (threadIdx.x >> 5);
    int lane = threadIdx.x & 31;
    if (gid >= N_NODES) return;
    int start = rowptr[gid];
    int cnt   = counts[gid];
    HOP_GATHER
    float nrm = norm[gid];
    float vv[4] = {acc.x * nrm, acc.y * nrm, acc.z * nrm, acc.w * nrm};
    ushort4 h, l;
    unsigned short* hp = (unsigned short*)&h;
    unsigned short* lp = (unsigned short*)&l;
    #pragma unroll
    for (int j = 0; j < 4; j++) {
        unsigned short hi = f32_to_bf16_rne(vv[j]);
        float fh = __uint_as_float((unsigned)hi << 16);
        hp[j] = hi;
        lp[j] = f32_to_bf16_rne(vv[j] - fh);
    }
    ((ushort4*)(ghi + (size_t)gid * IN_F))[lane] = h;
    ((ushort4*)(glo + (size_t)gid * IN_F))[lane] = l;
}

// ---------------- fused MLP via split-bf16 MFMA, weights-in-registers ----------------
// D = Ahi*Bhi + Ahi*Blo + Alo*Bhi (fp32 accum).
// Block: 4 waves, MB=32 rows (2 row-tiles of 16). Wave w owns GEMM1 cols
// [w*64, w*64+64): its 32 W1 fragments (128 VGPR) are preloaded ONCE, then the
// 2 row-tiles stream through with A double-buffered. GEMM2: waves 0-2 each own
// one 16-class col-tile with 16 W2 fragments (64 VGPR) preloaded.

#define LOAD_A(AH, AL, rt) do {                                              \
    const unsigned short* hp_ = h2hi + (size_t)(n0 + (rt) * 16 + lr) * IN_F + lg * 8; \
    const unsigned short* lp_ = h2lo + (size_t)(n0 + (rt) * 16 + lr) * IN_F + lg * 8; \
    _Pragma("unroll")                                                        \
    for (int kq = 0; kq < 4; kq++) {                                         \
        AH[kq] = *(const bf16x8*)(hp_ + kq * 32);                            \
        AL[kq] = *(const bf16x8*)(lp_ + kq * 32);                            \
    }                                                                        \
} while (0)

#define TILE(AH, AL, rt) do {                                                \
    _Pragma("unroll")                                                        \
    for (int ct = 0; ct < 4; ct++) {                                         \
        f32x4 acc = {0.f, 0.f, 0.f, 0.f};                                    \
        _Pragma("unroll")                                                    \
        for (int kq = 0; kq < 4; kq++) {                                     \
            acc = MFMA(AH[kq], b1h[ct][kq], acc);                            \
            acc = MFMA(AH[kq], b1l[ct][kq], acc);                            \
            acc = MFMA(AL[kq], b1h[ct][kq], acc);                            \
        }                                                                    \
        int col_ = w * 64 + ct * 16 + lr;                                    \
        _Pragma("unroll")                                                    \
        for (int r = 0; r < 4; r++) {                                        \
            int row_ = (rt) * 16 + lg * 4 + r;                               \
            float v_ = acc[r] + b1v[ct];                                     \
            v_ = v_ > 0.f ? v_ : 0.f;                                        \
            unsigned short hi_ = f32_to_bf16_rne(v_);                        \
            float fh_ = __uint_as_float((unsigned)hi_ << 16);                \
            tshi[row_ * TS_LD + col_] = hi_;                                 \
            tslo[row_ * TS_LD + col_] = f32_to_bf16_rne(v_ - fh_);           \
        }                                                                    \
    }                                                                        \
} while (0)

__global__ __launch_bounds__(256, 2) void k_mlp(
        const unsigned short* __restrict__ h2hi, const unsigned short* __restrict__ h2lo,
        const unsigned short* __restrict__ w1hi, const unsigned short* __restrict__ w1lo,
        const float* __restrict__ b1,
        const unsigned short* __restrict__ w2hi, const unsigned short* __restrict__ w2lo,
        const float* __restrict__ b2,
        float* __restrict__ out) {
    __shared__ __align__(16) unsigned short tshi[MB * TS_LD];  // 16.5 KB
    __shared__ __align__(16) unsigned short tslo[MB * TS_LD];  // 16.5 KB
    int n0 = blockIdx.x * MB;
    int t  = threadIdx.x;
    int w  = t >> 6;
    int l  = t & 63;
    int lr = l & 15;     // A-row / B-col within tile
    int lg = l >> 4;     // k-group

    // ---- preload W1 fragments for this wave's 64 cols: 32 frags = 128 VGPR ----
    bf16x8 b1h[4][4], b1l[4][4];
    float  b1v[4];
    #pragma unroll
    for (int ct = 0; ct < 4; ct++) {
        int col = w * 64 + ct * 16 + lr;
        const unsigned short* bhp = w1hi + (size_t)col * IN_F + lg * 8;
        const unsigned short* blp = w1lo + (size_t)col * IN_F + lg * 8;
        #pragma unroll
        for (int kq = 0; kq < 4; kq++) {
            b1h[ct][kq] = *(const bf16x8*)(bhp + kq * 32);
            b1l[ct][kq] = *(const bf16x8*)(blp + kq * 32);
        }
        b1v[ct] = b1[col];
    }

    // ---- GEMM1 over 2 row-tiles, A double-buffered ----
    bf16x8 aAh[4], aAl[4], aBh[4], aBl[4];
    LOAD_A(aAh, aAl, 0);
    LOAD_A(aBh, aBl, 1);
    TILE(aAh, aAl, 0);
    TILE(aBh, aBl, 1);
    __syncthreads();

    // ---- GEMM2: waves 0-2, one 16-class col-tile each, W2 frags in regs ----
    if (w < 3) {
        int col = w * 16 + lr;                     // 0..47 (padded)
        bf16x8 b2h[8], b2l[8];
        const unsigned short* bhp = w2hi + (size_t)col * HID_F + lg * 8;
        const unsigned short* blp = w2lo + (size_t)col * HID_F + lg * 8;
        #pragma unroll
        for (int kk = 0; kk < 8; kk++) {
            b2h[kk] = *(const bf16x8*)(bhp + kk * 32);
            b2l[kk] = *(const bf16x8*)(blp + kk * 32);
        }
        float bias = (col < CLS_F) ? b2[col] : 0.f;
        #pragma unroll
        for (int rt2 = 0; rt2 < 2; rt2++) {
            const unsigned short* ahp = tshi + (rt2 * 16 + lr) * TS_LD + lg * 8;
            const unsigned short* alp = tslo + (rt2 * 16 + lr) * TS_LD + lg * 8;
            f32x4 acc0 = {0.f, 0.f, 0.f, 0.f};
            f32x4 acc1 = {0.f, 0.f, 0.f, 0.f};
            #pragma unroll
            for (int kk = 0; kk < 4; kk++) {
                bf16x8 a_h0 = *(const bf16x8*)(ahp + kk * 32);
                bf16x8 a_l0 = *(const bf16x8*)(alp + kk * 32);
                bf16x8 a_h1 = *(const bf16x8*)(ahp + (kk + 4) * 32);
                bf16x8 a_l1 = *(const bf16x8*)(alp + (kk + 4) * 32);
                acc0 = MFMA(a_h0, b2h[kk], acc0);
                acc1 = MFMA(a_h1, b2h[kk + 4], acc1);
                acc0 = MFMA(a_h0, b2l[kk], acc0);
                acc1 = MFMA(a_h1, b2l[kk + 4], acc1);
                acc0 = MFMA(a_l0, b2h[kk], acc0);
                acc1 = MFMA(a_l1, b2h[kk + 4], acc1);
            }
            if (col < CLS_F) {
                #pragma unroll
                for (int r = 0; r < 4; r++) {
                    int mrow = n0 + rt2 * 16 + lg * 4 + r;
                    out[(size_t)mrow * CLS_F + col] = acc0[r] + acc1[r] + bias;
                }
            }
        }
    }
}

// ---------------- launch ----------------

extern "C" void kernel_launch(void* const* d_in, const int* in_sizes, int n_in,
                              void* d_out, int out_size, void* d_ws, size_t ws_size,
                              hipStream_t stream) {
    const float* features = (const float*)d_in[0];
    const int*   src      = (const int*)d_in[1];
    const int*   dst      = (const int*)d_in[2];
    const float* W1       = (const float*)d_in[3];
    const float* b1       = (const float*)d_in[4];
    const float* W2       = (const float*)d_in[5];
    const float* b2       = (const float*)d_in[6];
    float*       out      = (float*)d_out;

    char* ws = (char*)d_ws;
    size_t off = 0;
    auto alloc = [&](size_t bytes) -> void* {
        void* p = ws + off;
        off += (bytes + 255) & ~(size_t)255;
        return p;
    };
    int*   counts = (int*)alloc((size_t)N_NODES * 4);
    int*   rowptr = (int*)alloc((size_t)N_NODES * 4);
    int*   cursor = (int*)alloc((size_t)N_NODES * 4);
    int*   bsum   = (int*)alloc(256 * 4);
    float* norm   = (float*)alloc((size_t)N_NODES * 4);
    float* norm2  = (float*)alloc((size_t)N_NODES * 4);
    int*   csr    = (int*)alloc((size_t)N_EDGES * 4);
    float* h1     = (float*)alloc((size_t)N_NODES * IN_F * 4);
    unsigned short* h2hi = (unsigned short*)alloc((size_t)N_NODES * IN_F * 2);
    unsigned short* h2lo = (unsigned short*)alloc((size_t)N_NODES * IN_F * 2);
    unsigned short* w1hi = (unsigned short*)alloc((size_t)HID_F * IN_F * 2);
    unsigned short* w1lo = (unsigned short*)alloc((size_t)HID_F * IN_F * 2);
    unsigned short* w2hi = (unsigned short*)alloc((size_t)CLS_P * HID_F * 2);
    unsigned short* w2lo = (unsigned short*)alloc((size_t)CLS_P * HID_F * 2);

    hipMemsetAsync(counts, 0, (size_t)N_NODES * 4, stream);

    int nb = (N_NODES + 255) / 256;   // 157
    k_count<<<(N_EDGES + 255) / 256, 256, 0, stream>>>(dst, counts);
    k_prep<<<(IN_F * HID_F + CLS_P * HID_F + 255) / 256, 256, 0, stream>>>(
        W1, W2, w1hi, w1lo, w2hi, w2lo);
    k_scan1<<<nb, 256, 0, stream>>>(counts, bsum);
    k_scan2<<<1, 256, 0, stream>>>(bsum, nb);
    k_scan3<<<nb, 256, 0, stream>>>(counts, bsum, rowptr, cursor);
    k_norm<<<nb, 256, 0, stream>>>(counts, norm, norm2);
    k_fill<<<(N_EDGES + 255) / 256, 256, 0, stream>>>(src, dst, cursor, csr);

    // hop1: scale by norm[src]; hop2: scale by norm^2[src], trailing norm + bf16 split fused
    k_hop<<<(N_NODES + 7) / 8, 256, 0, stream>>>(features, h1, csr, rowptr, counts, norm);
    k_hop_split<<<(N_NODES + 7) / 8, 256, 0, stream>>>(h1, h2hi, h2lo, csr, rowptr, counts,
                                                       norm2, norm);

    k_mlp<<<N_NODES / MB, 256, 0, stream>>>(h2hi, h2lo, w1hi, w1lo, b1, w2hi, w2lo, b2, out);
}